// Round 15
// baseline (342.740 us; speedup 1.0000x reference)
//
#include <hip/hip_runtime.h>
#include <hip/hip_bf16.h>

// Problem constants
#define T_TOK 2048      // B*S
#define DDIM  1024
#define EEXP  8
#define KTOP  2
#define HDIM  2816
#define HSDIM 1536
#define BK    64
#define MT    256       // GEMM m-tile (512-thread kernels)
#define NB_UP 22        // HDIM/128
#define NB_SH 12        // HSDIM/128
#define NB_DN 8         // DDIM/128
#define GRID_UP 608     // max live: 12*31 + 10*23 = 602
#define GRID_DN 256     // max live: 8*31 = 248

typedef float f32x4 __attribute__((ext_vector_type(4)));
typedef short bf16x8 __attribute__((ext_vector_type(8)));

__device__ __forceinline__ unsigned short f2bf(float f) {
    __hip_bfloat16 h = __float2bfloat16(f);
    return __builtin_bit_cast(unsigned short, h);
}

// async global->LDS, 16B per lane; LDS dest = wave-uniform base + lane*16
__device__ __forceinline__ void gload16(const void* g, void* l) {
    __builtin_amdgcn_global_load_lds(
        (const __attribute__((address_space(1))) unsigned int*)g,
        (__attribute__((address_space(3))) unsigned int*)l, 16, 0, 0);
}

// Bijective chunked XCD remap over a RUNTIME live count (m204 general form).
__device__ __forceinline__ int xcd_live_map(int i, int n) {
    int q = n >> 3, r = n & 7;
    int xcd = i & 7, loc = i >> 3;
    int cap = q + (xcd < r ? 1 : 0);
    if (loc >= cap) return -1;
    return (xcd < r ? xcd * (q + 1) : r * (q + 1) + (xcd - r) * q) + loc;
}

// ---------------- small routing kernels ----------------

__global__ void init_k(int* counts, int* cursors) {
    if (threadIdx.x < EEXP) { counts[threadIdx.x] = 0; cursors[threadIdx.x] = 0; }
}

__global__ void gate_k(const float* __restrict__ X, const float* __restrict__ GW,
                       int* __restrict__ topi, float* __restrict__ topw,
                       int* __restrict__ counts) {
    int lane = threadIdx.x & 63;
    int t = blockIdx.x * 4 + (threadIdx.x >> 6);
    int e  = lane >> 3;
    int c8 = lane & 7;
    const float* xr = X + (size_t)t * DDIM;
    const float* gr = GW + (size_t)e * DDIM;
    float acc = 0.f;
#pragma unroll 8
    for (int j = 0; j < 32; j++) {
        int d = (c8 + 8 * j) * 4;
        float4 xv = *(const float4*)(xr + d);
        float4 gv = *(const float4*)(gr + d);
        acc += xv.x * gv.x + xv.y * gv.y + xv.z * gv.z + xv.w * gv.w;
    }
    acc += __shfl_xor(acc, 1);
    acc += __shfl_xor(acc, 2);
    acc += __shfl_xor(acc, 4);
    float p[8];
#pragma unroll
    for (int q = 0; q < 8; q++) p[q] = __shfl(acc, q * 8);
    float mx = p[0];
#pragma unroll
    for (int q = 1; q < 8; q++) mx = fmaxf(mx, p[q]);
    float s = 0.f;
#pragma unroll
    for (int q = 0; q < 8; q++) { p[q] = expf(p[q] - mx); s += p[q]; }
    float inv = 1.f / s;
#pragma unroll
    for (int q = 0; q < 8; q++) p[q] *= inv;
    float v1 = -1.f; int i1 = 0;
#pragma unroll
    for (int q = 0; q < 8; q++) { if (p[q] > v1) { v1 = p[q]; i1 = q; } }
    float v2 = -1.f; int i2 = 0;
#pragma unroll
    for (int q = 0; q < 8; q++) { if (q != i1 && p[q] > v2) { v2 = p[q]; i2 = q; } }
    if (lane == 0) {
        topi[2 * t] = i1; topi[2 * t + 1] = i2;
        topw[2 * t] = v1; topw[2 * t + 1] = v2;
        atomicAdd(&counts[i1], 1);
        atomicAdd(&counts[i2], 1);
    }
}

// prefix-sum + device-built tile worklist: (e<<16)|m0 ; routed tiles FIRST,
// then shared-expert (e=8) tiles. wl_n[0]=total items, wl_n[1]=routed items.
__global__ void scan_k(const int* __restrict__ counts, int* __restrict__ offsets,
                       int* __restrict__ wl, int* __restrict__ wl_n) {
    if (threadIdx.x == 0) {
        int s = 0;
        for (int e = 0; e < EEXP; e++) { offsets[e] = s; s += counts[e]; }
        offsets[EEXP] = s;
        int n = 0;
        for (int e = 0; e < EEXP; e++) {
            int Ne = counts[e];
            for (int m0 = 0; m0 < Ne; m0 += MT) wl[n++] = (e << 16) | m0;
        }
        wl_n[1] = n;                       // routed count
        for (int m0 = 0; m0 < T_TOK; m0 += MT) wl[n++] = (EEXP << 16) | m0;
        wl_n[0] = n;                       // total (<= 31)
    }
}

__global__ void build_k(const int* __restrict__ topi, const float* __restrict__ topw,
                        const int* __restrict__ offsets,
                        int* __restrict__ cursors, int* __restrict__ rows_token,
                        float* __restrict__ gate_row) {
    int t = blockIdx.x * 256 + threadIdx.x;
    if (t >= T_TOK) return;
    for (int k = 0; k < KTOP; k++) {
        int e = topi[2 * t + k];
        int pos = atomicAdd(&cursors[e], 1);
        int r = offsets[e] + pos;
        rows_token[r] = t;
        gate_row[r] = topw[2 * t + k];
    }
}

// ---------------- pre-pass: cast & transpose into CHUNKED layout ----------------
// Chunked transposed-weight layout (GEMM gathers per-lane, so layout is free):
//   Wt_c[(kb*Nn + n)*32 + c4*8 + e] = bf16(W[kb*32 + c4*8 + e][n])
// 32(k) x 256(n) tile; gload_lds staging; c4-dependent source chunk XOR matched
// on the b128 readback (rule #21). R12-proven (0 conflicts). prep rate is the
// empirical floor (~4 TB/s logical combined) per R6-R13 five-variant sweep.
__device__ __forceinline__ void tcast_tile(const float* __restrict__ S,
                                           unsigned short* __restrict__ Dc,
                                           int Kd, int Nn, int k0, int n0,
                                           float* __restrict__ ld /*[32*256]*/) {
    int tid = threadIdx.x, lane = tid & 63, w = tid >> 6;
#pragma unroll
    for (int j = 0; j < 8; j++) {
        int r = j * 4 + w;                         // k-row 0..31 (wave-uniform)
        int f = ((r >> 3) & 3) << 2;               // c4-dependent chunk XOR
        gload16(S + (size_t)(k0 + r) * Nn + n0 + (lane ^ f) * 4, ld + r * 256);
    }
    __syncthreads();
    int c4 = tid & 3;                              // k-sub block (rows c4*8..+7)
    int nq = tid >> 2;                             // n-quad 0..63
    int f  = c4 << 2;
    f32x4 blk[8];
#pragma unroll
    for (int jj = 0; jj < 8; jj++) {
        int r = c4 * 8 + jj;
        blk[jj] = *(const f32x4*)(ld + r * 256 + ((nq ^ f) & 63) * 4);
    }
    size_t kb = (size_t)(k0 >> 5);
#pragma unroll
    for (int v = 0; v < 4; v++) {
        unsigned short o[8];
#pragma unroll
        for (int jj = 0; jj < 8; jj++) o[jj] = f2bf(blk[jj][v]);
        *(uint4*)(Dc + (kb * Nn + n0 + nq * 4 + v) * 32 + c4 * 8) = *(const uint4*)o;
    }
}

// job table. W2 jobs FIRST when enabled (W2's f32 reads happen BEFORE W1t/W3t
// outputs fill L3, so fused_up still finds them warm — R8/R14 lesson):
#define PREP_GRID     7232
#define PREP_GRID_W2 10048

__global__ __launch_bounds__(256) void prep_k(
    const float* __restrict__ x,
    const float* __restrict__ w1, const float* __restrict__ w3,
    const float* __restrict__ sw1, const float* __restrict__ sw3,
    const float* __restrict__ sw2, const float* __restrict__ w2,
    unsigned short* __restrict__ Xb,
    unsigned short* __restrict__ W1t, unsigned short* __restrict__ W3t,
    unsigned short* __restrict__ sw1t, unsigned short* __restrict__ sw3t,
    unsigned short* __restrict__ sw2t, unsigned short* __restrict__ W2t,
    int withW2)
{
    __shared__ __align__(16) float ld[32 * 256];
    int b = blockIdx.x;
    const size_t DH = (size_t)DDIM * HDIM;
    if (withW2) {
        if (b < 2816) {   // W2 [z][HDIM][DDIM] -> chunked W2t, FIRST
            int z = b / 352, r = b % 352;
            tcast_tile(w2 + z * DH, W2t + z * DH, HDIM, DDIM,
                       (r / 4) * 32, (r % 4) * 256, ld);
            return;
        }
        b -= 2816;
    }
    if (b >= 6208) {
        int i = (b - 6208) * 2048 + threadIdx.x * 8;
        float4 a = *(const float4*)(x + i);
        float4 c = *(const float4*)(x + i + 4);
        unsigned short o[8] = { f2bf(a.x), f2bf(a.y), f2bf(a.z), f2bf(a.w),
                                f2bf(c.x), f2bf(c.y), f2bf(c.z), f2bf(c.w) };
        *(uint4*)(Xb + i) = *(const uint4*)o;
        return;
    }
    const float* S; unsigned short* D; int Kd, Nn, k0, n0;
    if (b < 2816) {
        int z = b / 352, r = b % 352;
        Kd = DDIM; Nn = HDIM;
        S = w1 + z * DH; D = W1t + z * DH;
        k0 = (r / 11) * 32; n0 = (r % 11) * 256;
    } else if (b < 5632) {
        int idx = b - 2816, z = idx / 352, r = idx % 352;
        Kd = DDIM; Nn = HDIM;
        S = w3 + z * DH; D = W3t + z * DH;
        k0 = (r / 11) * 32; n0 = (r % 11) * 256;
    } else if (b < 5824) {
        int idx = b - 5632;
        Kd = DDIM; Nn = HSDIM; S = sw1; D = sw1t;
        k0 = (idx / 6) * 32; n0 = (idx % 6) * 256;
    } else if (b < 6016) {
        int idx = b - 5824;
        Kd = DDIM; Nn = HSDIM; S = sw3; D = sw3t;
        k0 = (idx / 6) * 32; n0 = (idx % 6) * 256;
    } else {
        int idx = b - 6016;
        Kd = HSDIM; Nn = DDIM; S = sw2; D = sw2t;
        k0 = (idx / 4) * 32; n0 = (idx % 4) * 256;
    }
    tcast_tile(S, D, Kd, Nn, k0, n0, ld);
    (void)Kd;
}

// Fallback W2 transpose (aliased region, runs after fused_up) if ws too small.
__global__ __launch_bounds__(256) void tcast_k(const float* __restrict__ S,
                                               unsigned short* __restrict__ Dm) {
    __shared__ __align__(16) float ld[32 * 256];
    int b = blockIdx.x;                 // 8 experts x 352 tiles
    int z = b / 352, r = b % 352;
    size_t zo = (size_t)z * HDIM * DDIM;
    tcast_tile(S + zo, Dm + zo, HDIM, DDIM, (r / 4) * 32, (r % 4) * 256, ld);
}

// ---------------- fused up-projection: H = silu(X@W1) * (X@W3) ----------------
// 512 threads, tile 256(M) x 128(N), BK=64, 8 waves (4m x 2n, per-wave 64x64).
// T3+T4 counted-vmcnt 2-deep pipeline: raw s_barrier, vmcnt(8) steady (never 0
// in-loop), prefetch stays in flight across barriers. sched_barrier(0) pins
// compute between barriers (rule #18). LDS 128 KB -> 1 block/CU, 2 waves/SIMD.
__global__ __launch_bounds__(512, 2) void fused_up(
    const unsigned short* __restrict__ Xb,
    const int* __restrict__ rows_token,
    const int* __restrict__ offsets,
    const unsigned short* __restrict__ W1t,   // [8] chunked (Nn=HDIM)
    const unsigned short* __restrict__ W3t,
    const unsigned short* __restrict__ sw1t,  // chunked (Nn=HSDIM)
    const unsigned short* __restrict__ sw3t,
    unsigned short* __restrict__ Hg,          // [4096][H]
    unsigned short* __restrict__ Hs,          // [2048][HS]
    const int* __restrict__ wl, const int* __restrict__ wl_n)
{
    int n_all = wl_n[0], n_r = wl_n[1];
    int live = NB_SH * n_all + (NB_UP - NB_SH) * n_r;
    int L = xcd_live_map(blockIdx.x, live);
    if (L < 0 || L >= live) return;
    int nb, it;
    if (L < NB_SH * n_all) { nb = L / n_all; it = L % n_all; }
    else { int L2 = L - NB_SH * n_all; nb = NB_SH + L2 / n_r; it = L2 % n_r; }
    int pk = wl[it];
    int z = pk >> 16, m0 = pk & 0xffff;
    bool sh = (z == EEXP);
    int roff, Ne, Nn;
    const unsigned short *w1, *w3;
    unsigned short* Ho;
    if (sh) { roff = 0; Ne = T_TOK; Nn = HSDIM; w1 = sw1t; w3 = sw3t; Ho = Hs; }
    else {
        roff = offsets[z]; Ne = offsets[z + 1] - roff; Nn = HDIM;
        w1 = W1t + (size_t)z * HDIM * DDIM;
        w3 = W3t + (size_t)z * HDIM * DDIM;
        Ho = Hg;
    }
    int n0 = nb * 128;
    if (n0 >= Nn) return;

    __shared__ __align__(16) unsigned short As [2][256 * 64];   // 64 KB
    __shared__ __align__(16) unsigned short B1s[2][128 * 64];   // 32 KB
    __shared__ __align__(16) unsigned short B3s[2][128 * 64];   // 32 KB

    int tid = threadIdx.x, lane = tid & 63, wid = tid >> 6;
    int wr = wid >> 1, wc = wid & 1;          // per-wave 64 rows x 64 cols
    int cl = (lane & 7) ^ (lane >> 3);        // swizzled chunk index 0..7

    size_t bstep = (size_t)64 * Nn;           // chunked-layout K-step stride (u16)
    const unsigned short* pA[4];
    const unsigned short *pB1[2], *pB3[2];
#pragma unroll
    for (int j = 0; j < 4; j++) {
        int lr = (wid * 4 + j) * 8 + (lane >> 3);       // 0..255
        int gr = m0 + lr; if (gr >= Ne) gr = Ne - 1;
        int tok = sh ? gr : rows_token[roff + gr];
        pA[j] = Xb + (size_t)tok * DDIM + cl * 8;
    }
#pragma unroll
    for (int j = 0; j < 2; j++) {
        int lr = (wid * 2 + j) * 8 + (lane >> 3);       // 0..127
        size_t boff = ((size_t)(cl >> 2) * Nn + n0 + lr) * 32 + (cl & 3) * 8;
        pB1[j] = w1 + boff;
        pB3[j] = w3 + boff;
    }

    // 8 gload16/thread/K-step (4 A + 2 B1 + 2 B3)
#define FSTAGE(buf)                                                         \
    {                                                                       \
        _Pragma("unroll")                                                   \
        for (int j = 0; j < 4; j++) {                                       \
            gload16(pA[j], &As[buf][(wid * 4 + j) * 512]); pA[j] += BK;     \
        }                                                                   \
        _Pragma("unroll")                                                   \
        for (int j = 0; j < 2; j++) {                                       \
            gload16(pB1[j], &B1s[buf][(wid * 2 + j) * 512]); pB1[j] += bstep; \
            gload16(pB3[j], &B3s[buf][(wid * 2 + j) * 512]); pB3[j] += bstep; \
        }                                                                   \
    }

    const f32x4 fz = {0.f, 0.f, 0.f, 0.f};
    f32x4 acc1[4][4], acc3[4][4];
#pragma unroll
    for (int mi = 0; mi < 4; mi++)
#pragma unroll
        for (int nj = 0; nj < 4; nj++) { acc1[mi][nj] = fz; acc3[mi][nj] = fz; }

    FSTAGE(0)
    FSTAGE(1)

    int r = lane & 15, h = lane >> 4, sw = (lane & 7) << 4;
#pragma unroll 1
    for (int ks = 0; ks < 16; ks++) {          // DDIM/BK == 16
        int cur = ks & 1;
        if (ks == 15) asm volatile("s_waitcnt vmcnt(0)" ::: "memory");
        else          asm volatile("s_waitcnt vmcnt(8)" ::: "memory");
        __builtin_amdgcn_s_barrier();          // buf[cur] complete block-wide
        __builtin_amdgcn_sched_barrier(0);
        const unsigned short* Ac  = As[cur];
        const unsigned short* B1c = B1s[cur];
        const unsigned short* B3c = B3s[cur];
#pragma unroll
        for (int kk = 0; kk < 2; kk++) {
            int cb = (kk * 64 + h * 16) ^ sw;
            bf16x8 a[4], b1[4], b3[4];
#pragma unroll
            for (int mi = 0; mi < 4; mi++)
                a[mi] = *(const bf16x8*)((const char*)Ac + (wr * 64 + mi * 16 + r) * 128 + cb);
#pragma unroll
            for (int nj = 0; nj < 4; nj++) {
                b1[nj] = *(const bf16x8*)((const char*)B1c + (wc * 64 + nj * 16 + r) * 128 + cb);
                b3[nj] = *(const bf16x8*)((const char*)B3c + (wc * 64 + nj * 16 + r) * 128 + cb);
            }
#pragma unroll
            for (int mi = 0; mi < 4; mi++)
#pragma unroll
                for (int nj = 0; nj < 4; nj++) {
                    acc1[mi][nj] = __builtin_amdgcn_mfma_f32_16x16x32_bf16(a[mi], b1[nj], acc1[mi][nj], 0, 0, 0);
                    acc3[mi][nj] = __builtin_amdgcn_mfma_f32_16x16x32_bf16(a[mi], b3[nj], acc3[mi][nj], 0, 0, 0);
                }
        }
        __builtin_amdgcn_sched_barrier(0);
        __builtin_amdgcn_s_barrier();          // all waves done reading buf[cur]
        if (ks + 2 < 16) FSTAGE(cur)           // overwrite cur with tile ks+2
    }
#undef FSTAGE
#pragma unroll
    for (int mi = 0; mi < 4; mi++) {
#pragma unroll
        for (int nj = 0; nj < 4; nj++) {
            int col = n0 + wc * 64 + nj * 16 + r;
#pragma unroll
            for (int j = 0; j < 4; j++) {
                int row = wr * 64 + mi * 16 + h * 4 + j;
                if (m0 + row < Ne) {
                    float aa = acc1[mi][nj][j], bb = acc3[mi][nj][j];
                    float hv = (aa / (1.f + expf(-aa))) * bb;
                    Ho[(size_t)(roff + m0 + row) * Nn + col] = f2bf(hv);
                }
            }
        }
    }
}

// ---------------- down-projection + combine: out += gate * (H @ W2) ----------------
// 512 threads, tile 256(M) x 128(N), BK=64; same counted-vmcnt pipeline
// (6 loads/thread/step -> vmcnt(6) steady). Epilogue: gated atomicAdd into
// pre-zeroed out (routed x gate, shared x 1). LDS 96 KB.
__global__ __launch_bounds__(512, 2) void gemm2(
    const unsigned short* __restrict__ Hg,
    const unsigned short* __restrict__ Hs,
    const unsigned short* __restrict__ W2t,   // [8] chunked (Nn=DDIM)
    const unsigned short* __restrict__ sw2t,  // chunked (Nn=DDIM)
    const int* __restrict__ offsets,
    const int* __restrict__ rows_token,
    const float* __restrict__ gate_row,
    float* __restrict__ out,
    const int* __restrict__ wl, const int* __restrict__ wl_n)
{
    int n_all = wl_n[0];
    int live = NB_DN * n_all;
    int L = xcd_live_map(blockIdx.x, live);
    if (L < 0 || L >= live) return;
    int nb = L / n_all, it = L % n_all;
    int pk = wl[it];
    int z = pk >> 16, m0 = pk & 0xffff;
    bool sh = (z == EEXP);
    int roff, Ne, Kd;
    const unsigned short *Ab, *Bb;
    if (sh) { roff = 0; Ne = T_TOK; Kd = HSDIM; Ab = Hs; Bb = sw2t; }
    else {
        roff = offsets[z]; Ne = offsets[z + 1] - roff; Kd = HDIM;
        Ab = Hg + (size_t)roff * HDIM;
        Bb = W2t + (size_t)z * DDIM * HDIM;
    }
    int n0 = nb * 128;

    __shared__ __align__(16) unsigned short As[2][256 * 64];   // 64 KB
    __shared__ __align__(16) unsigned short Bs[2][128 * 64];   // 32 KB

    int tid = threadIdx.x, lane = tid & 63, wid = tid >> 6;
    int wr = wid >> 1, wc = wid & 1;
    int cl = (lane & 7) ^ (lane >> 3);

    const size_t bstep = (size_t)64 * DDIM;   // chunked stride (u16), Nn = DDIM
    const unsigned short* pA[4];
    const unsigned short* pB[2];
#pragma unroll
    for (int j = 0; j < 4; j++) {
        int lr = (wid * 4 + j) * 8 + (lane >> 3);       // 0..255
        int gr = m0 + lr; if (gr >= Ne) gr = Ne - 1;
        pA[j] = Ab + (size_t)gr * Kd + cl * 8;
    }
#pragma unroll
    for (int j = 0; j < 2; j++) {
        int lr = (wid * 2 + j) * 8 + (lane >> 3);       // 0..127
        pB[j] = Bb + ((size_t)(cl >> 2) * DDIM + n0 + lr) * 32 + (cl & 3) * 8;
    }

#define G2STAGE(buf)                                                        \
    {                                                                       \
        _Pragma("unroll")                                                   \
        for (int j = 0; j < 4; j++) {                                       \
            gload16(pA[j], &As[buf][(wid * 4 + j) * 512]); pA[j] += BK;     \
        }                                                                   \
        _Pragma("unroll")                                                   \
        for (int j = 0; j < 2; j++) {                                       \
            gload16(pB[j], &Bs[buf][(wid * 2 + j) * 512]); pB[j] += bstep;  \
        }                                                                   \
    }

    const f32x4 fz = {0.f, 0.f, 0.f, 0.f};
    f32x4 acc[4][4];
#pragma unroll
    for (int mi = 0; mi < 4; mi++)
#pragma unroll
        for (int nj = 0; nj < 4; nj++) acc[mi][nj] = fz;

    G2STAGE(0)
    G2STAGE(1)

    int nks = Kd / BK;
    int r = lane & 15, h = lane >> 4, sw = (lane & 7) << 4;
#pragma unroll 1
    for (int ks = 0; ks < nks; ks++) {
        int cur = ks & 1;
        if (ks == nks - 1) asm volatile("s_waitcnt vmcnt(0)" ::: "memory");
        else               asm volatile("s_waitcnt vmcnt(6)" ::: "memory");
        __builtin_amdgcn_s_barrier();
        __builtin_amdgcn_sched_barrier(0);
        const unsigned short* Ac = As[cur];
        const unsigned short* Bc = Bs[cur];
#pragma unroll
        for (int kk = 0; kk < 2; kk++) {
            int cb = (kk * 64 + h * 16) ^ sw;
            bf16x8 a[4], b[4];
#pragma unroll
            for (int mi = 0; mi < 4; mi++)
                a[mi] = *(const bf16x8*)((const char*)Ac + (wr * 64 + mi * 16 + r) * 128 + cb);
#pragma unroll
            for (int nj = 0; nj < 4; nj++)
                b[nj] = *(const bf16x8*)((const char*)Bc + (wc * 64 + nj * 16 + r) * 128 + cb);
#pragma unroll
            for (int mi = 0; mi < 4; mi++)
#pragma unroll
                for (int nj = 0; nj < 4; nj++)
                    acc[mi][nj] = __builtin_amdgcn_mfma_f32_16x16x32_bf16(a[mi], b[nj], acc[mi][nj], 0, 0, 0);
        }
        __builtin_amdgcn_sched_barrier(0);
        __builtin_amdgcn_s_barrier();
        if (ks + 2 < nks) G2STAGE(cur)
    }
#undef G2STAGE
#pragma unroll
    for (int mi = 0; mi < 4; mi++) {
#pragma unroll
        for (int j = 0; j < 4; j++) {
            int row = wr * 64 + mi * 16 + h * 4 + j;
            if (m0 + row >= Ne) continue;
            int tok; float g;
            if (sh) { tok = m0 + row; g = 1.f; }
            else {
                int rr = roff + m0 + row;
                tok = rows_token[rr];
                g = gate_row[rr];
            }
            float* orow = out + (size_t)tok * DDIM;
#pragma unroll
            for (int nj = 0; nj < 4; nj++) {
                int col = n0 + wc * 64 + nj * 16 + r;
                atomicAdd(orow + col, g * acc[mi][nj][j]);
            }
        }
    }
}

// ---------------- launch ----------------
extern "C" void kernel_launch(void* const* d_in, const int* in_sizes, int n_in,
                              void* d_out, int out_size, void* d_ws, size_t ws_size,
                              hipStream_t stream) {
    const float* x   = (const float*)d_in[0];
    const float* gw  = (const float*)d_in[1];
    const float* w1  = (const float*)d_in[2];
    const float* w3  = (const float*)d_in[3];
    const float* w2  = (const float*)d_in[4];
    const float* sw1 = (const float*)d_in[5];
    const float* sw3 = (const float*)d_in[6];
    const float* sw2 = (const float*)d_in[7];
    float* out = (float*)d_out;
    char* ws = (char*)d_ws;

    const size_t MB = 1048576;
    int*   counts     = (int*)(ws);
    int*   offsets    = (int*)(ws + 64);
    int*   cursors    = (int*)(ws + 128);
    int*   wl_n       = (int*)(ws + 192);     // [0]=total, [1]=routed
    int*   wl         = (int*)(ws + 256);
    int*   topi       = (int*)(ws + 512);
    float* topw       = (float*)(ws + 16896);
    int*   rows_token = (int*)(ws + 33280);
    float* gate_row   = (float*)(ws + 49664);
    unsigned short* Xb   = (unsigned short*)(ws + 1 * MB);    // 4 MB
    unsigned short* sw1t = (unsigned short*)(ws + 6 * MB);    // 3 MB
    unsigned short* sw3t = (unsigned short*)(ws + 9 * MB);    // 3 MB
    unsigned short* sw2t = (unsigned short*)(ws + 12 * MB);   // 3 MB
    unsigned short* Hg   = (unsigned short*)(ws + 16 * MB);   // 22 MB
    unsigned short* Hs   = (unsigned short*)(ws + 40 * MB);   // 6 MB
    unsigned short* W1t  = (unsigned short*)(ws + 64 * MB);   // 44 MB
    unsigned short* W3t  = (unsigned short*)(ws + 108 * MB);  // 44 MB (ends 152 MB)

    // W2t: separate region when workspace allows; else alias W1t + late transpose.
    bool sepW2 = (ws_size >= 196 * MB);
    unsigned short* W2t = sepW2 ? (unsigned short*)(ws + 152 * MB) : W1t;

    // routing
    init_k<<<1, 64, 0, stream>>>(counts, cursors);
    gate_k<<<T_TOK / 4, 256, 0, stream>>>(x, gw, topi, topw, counts);
    scan_k<<<1, 64, 0, stream>>>(counts, offsets, wl, wl_n);
    build_k<<<T_TOK / 256, 256, 0, stream>>>(topi, topw, offsets, cursors,
                                             rows_token, gate_row);

    // zero out (gemm2 accumulates into it atomically)
    hipMemsetAsync(out, 0, (size_t)T_TOK * DDIM * sizeof(float), stream);

    // pre-pass: W2 (first, when sepW2) + W1/W3/shared transposes + xcast
    prep_k<<<sepW2 ? PREP_GRID_W2 : PREP_GRID, 256, 0, stream>>>(
        x, w1, w3, sw1, sw3, sw2, w2,
        Xb, W1t, W3t, sw1t, sw3t, sw2t, W2t, sepW2 ? 1 : 0);

    // up-projection (counted-vmcnt pipelined)
    fused_up<<<GRID_UP, 512, 0, stream>>>(
        Xb, rows_token, offsets, W1t, W3t, sw1t, sw3t, Hg, Hs, wl, wl_n);

    // fallback W2 transpose into aliased region (only if ws too small)
    if (!sepW2)
        tcast_k<<<2816, 256, 0, stream>>>(w2, W2t);

    // down-projection + gated combine (atomicAdd into out), pipelined
    gemm2<<<GRID_DN, 512, 0, stream>>>(
        Hg, Hs, W2t, sw2t, offsets, rows_token, gate_row, out, wl, wl_n);
}

// Round 16
// 291.703 us; speedup vs baseline: 1.1750x; 1.1750x over previous
//
#include <hip/hip_runtime.h>
#include <hip/hip_bf16.h>

// Problem constants
#define T_TOK 2048      // B*S
#define DDIM  1024
#define EEXP  8
#define KTOP  2
#define HDIM  2816
#define HSDIM 1536
#define BK    64
#define MT    128       // GEMM m-tile
#define NB_UP 22        // HDIM/128
#define NB_SH 12        // HSDIM/128
#define NB_DN 8         // DDIM/128
#define GRID_UP 1072    // max live: 12*56 + 10*40
#define GRID_DN 448     // 8*56
#define TCAST_W2 2816   // W2 tcast blocks (8 experts x 88kb x 4nb)

typedef float f32x4 __attribute__((ext_vector_type(4)));
typedef short bf16x8 __attribute__((ext_vector_type(8)));

__device__ __forceinline__ unsigned short f2bf(float f) {
    __hip_bfloat16 h = __float2bfloat16(f);
    return __builtin_bit_cast(unsigned short, h);
}

// async global->LDS, 16B per lane; LDS dest = wave-uniform base + lane*16
__device__ __forceinline__ void gload16(const void* g, void* l) {
    __builtin_amdgcn_global_load_lds(
        (const __attribute__((address_space(1))) unsigned int*)g,
        (__attribute__((address_space(3))) unsigned int*)l, 16, 0, 0);
}

// Bijective chunked XCD remap over a RUNTIME live count (m204 general form).
__device__ __forceinline__ int xcd_live_map(int i, int n) {
    int q = n >> 3, r = n & 7;
    int xcd = i & 7, loc = i >> 3;
    int cap = q + (xcd < r ? 1 : 0);
    if (loc >= cap) return -1;
    return (xcd < r ? xcd * (q + 1) : r * (q + 1) + (xcd - r) * q) + loc;
}

// ---------------- small routing kernels ----------------

__global__ void init_k(int* counts, int* cursors) {
    if (threadIdx.x < EEXP) { counts[threadIdx.x] = 0; cursors[threadIdx.x] = 0; }
}

__global__ void gate_k(const float* __restrict__ X, const float* __restrict__ GW,
                       int* __restrict__ topi, float* __restrict__ topw,
                       int* __restrict__ counts) {
    int lane = threadIdx.x & 63;
    int t = blockIdx.x * 4 + (threadIdx.x >> 6);
    int e  = lane >> 3;
    int c8 = lane & 7;
    const float* xr = X + (size_t)t * DDIM;
    const float* gr = GW + (size_t)e * DDIM;
    float acc = 0.f;
#pragma unroll 8
    for (int j = 0; j < 32; j++) {
        int d = (c8 + 8 * j) * 4;
        float4 xv = *(const float4*)(xr + d);
        float4 gv = *(const float4*)(gr + d);
        acc += xv.x * gv.x + xv.y * gv.y + xv.z * gv.z + xv.w * gv.w;
    }
    acc += __shfl_xor(acc, 1);
    acc += __shfl_xor(acc, 2);
    acc += __shfl_xor(acc, 4);
    float p[8];
#pragma unroll
    for (int q = 0; q < 8; q++) p[q] = __shfl(acc, q * 8);
    float mx = p[0];
#pragma unroll
    for (int q = 1; q < 8; q++) mx = fmaxf(mx, p[q]);
    float s = 0.f;
#pragma unroll
    for (int q = 0; q < 8; q++) { p[q] = expf(p[q] - mx); s += p[q]; }
    float inv = 1.f / s;
#pragma unroll
    for (int q = 0; q < 8; q++) p[q] *= inv;
    float v1 = -1.f; int i1 = 0;
#pragma unroll
    for (int q = 0; q < 8; q++) { if (p[q] > v1) { v1 = p[q]; i1 = q; } }
    float v2 = -1.f; int i2 = 0;
#pragma unroll
    for (int q = 0; q < 8; q++) { if (q != i1 && p[q] > v2) { v2 = p[q]; i2 = q; } }
    if (lane == 0) {
        topi[2 * t] = i1; topi[2 * t + 1] = i2;
        topw[2 * t] = v1; topw[2 * t + 1] = v2;
        atomicAdd(&counts[i1], 1);
        atomicAdd(&counts[i2], 1);
    }
}

// prefix-sum + device-built tile worklist: (e<<16)|m0 ; routed tiles FIRST,
// then shared-expert (e=8) tiles. wl_n[0]=total items, wl_n[1]=routed items.
__global__ void scan_k(const int* __restrict__ counts, int* __restrict__ offsets,
                       int* __restrict__ wl, int* __restrict__ wl_n) {
    if (threadIdx.x == 0) {
        int s = 0;
        for (int e = 0; e < EEXP; e++) { offsets[e] = s; s += counts[e]; }
        offsets[EEXP] = s;
        int n = 0;
        for (int e = 0; e < EEXP; e++) {
            int Ne = counts[e];
            for (int m0 = 0; m0 < Ne; m0 += MT) wl[n++] = (e << 16) | m0;
        }
        wl_n[1] = n;                       // routed count
        for (int m0 = 0; m0 < T_TOK; m0 += MT) wl[n++] = (EEXP << 16) | m0;
        wl_n[0] = n;                       // total (<= 56)
    }
}

__global__ void build_k(const int* __restrict__ topi, const float* __restrict__ topw,
                        const int* __restrict__ offsets,
                        int* __restrict__ cursors, int* __restrict__ rows_token,
                        float* __restrict__ gate_row) {
    int t = blockIdx.x * 256 + threadIdx.x;
    if (t >= T_TOK) return;
    for (int k = 0; k < KTOP; k++) {
        int e = topi[2 * t + k];
        int pos = atomicAdd(&cursors[e], 1);
        int r = offsets[e] + pos;
        rows_token[r] = t;
        gate_row[r] = topw[2 * t + k];
    }
}

// ---------------- pre-pass: cast & transpose into CHUNKED layout ----------------
// Chunked transposed-weight layout (GEMM gathers per-lane, so layout is free):
//   Wt_c[(kb*Nn + n)*32 + c4*8 + e] = bf16(W[kb*32 + c4*8 + e][n])
// 32(k) x 256(n) tile; gload_lds staging; c4-dependent source chunk XOR matched
// on the b128 readback (rule #21). R12-proven (0 conflicts). prep rate is the
// empirical floor per the R6-R13 five-variant sweep — stop optimizing in-kernel.
__device__ __forceinline__ void tcast_tile(const float* __restrict__ S,
                                           unsigned short* __restrict__ Dc,
                                           int Kd, int Nn, int k0, int n0,
                                           float* __restrict__ ld /*[32*256]*/) {
    int tid = threadIdx.x, lane = tid & 63, w = tid >> 6;
#pragma unroll
    for (int j = 0; j < 8; j++) {
        int r = j * 4 + w;                         // k-row 0..31 (wave-uniform)
        int f = ((r >> 3) & 3) << 2;               // c4-dependent chunk XOR
        gload16(S + (size_t)(k0 + r) * Nn + n0 + (lane ^ f) * 4, ld + r * 256);
    }
    __syncthreads();
    int c4 = tid & 3;                              // k-sub block (rows c4*8..+7)
    int nq = tid >> 2;                             // n-quad 0..63
    int f  = c4 << 2;
    f32x4 blk[8];
#pragma unroll
    for (int jj = 0; jj < 8; jj++) {
        int r = c4 * 8 + jj;
        blk[jj] = *(const f32x4*)(ld + r * 256 + ((nq ^ f) & 63) * 4);
    }
    size_t kb = (size_t)(k0 >> 5);
#pragma unroll
    for (int v = 0; v < 4; v++) {
        unsigned short o[8];
#pragma unroll
        for (int jj = 0; jj < 8; jj++) o[jj] = f2bf(blk[jj][v]);
        *(uint4*)(Dc + (kb * Nn + n0 + nq * 4 + v) * 32 + c4 * 8) = *(const uint4*)o;
    }
}

// prep job table (W1/W3/shared/xcast; W2 handled by blocks merged into fused_up):
//  [0,2816)     w1  -> W1t   (z, 32kb x 11nb = 352)
//  [2816,5632)  w3  -> W3t
//  [5632,5824)  sw1 -> sw1t  (32kb x 6nb = 192)
//  [5824,6016)  sw3 -> sw3t
//  [6016,6208)  sw2 -> sw2t  (48kb x 4nb = 192)
//  [6208,7232)  xcast: X f32 -> Xb bf16
#define PREP_GRID 7232

__global__ __launch_bounds__(256) void prep_k(
    const float* __restrict__ x,
    const float* __restrict__ w1, const float* __restrict__ w3,
    const float* __restrict__ sw1, const float* __restrict__ sw3,
    const float* __restrict__ sw2,
    unsigned short* __restrict__ Xb,
    unsigned short* __restrict__ W1t, unsigned short* __restrict__ W3t,
    unsigned short* __restrict__ sw1t, unsigned short* __restrict__ sw3t,
    unsigned short* __restrict__ sw2t)
{
    __shared__ __align__(16) float ld[32 * 256];
    int b = blockIdx.x;
    const size_t DH = (size_t)DDIM * HDIM;
    if (b >= 6208) {
        int i = (b - 6208) * 2048 + threadIdx.x * 8;
        float4 a = *(const float4*)(x + i);
        float4 c = *(const float4*)(x + i + 4);
        unsigned short o[8] = { f2bf(a.x), f2bf(a.y), f2bf(a.z), f2bf(a.w),
                                f2bf(c.x), f2bf(c.y), f2bf(c.z), f2bf(c.w) };
        *(uint4*)(Xb + i) = *(const uint4*)o;
        return;
    }
    const float* S; unsigned short* D; int Kd, Nn, k0, n0;
    if (b < 2816) {
        int z = b / 352, r = b % 352;
        Kd = DDIM; Nn = HDIM;
        S = w1 + z * DH; D = W1t + z * DH;
        k0 = (r / 11) * 32; n0 = (r % 11) * 256;
    } else if (b < 5632) {
        int idx = b - 2816, z = idx / 352, r = idx % 352;
        Kd = DDIM; Nn = HDIM;
        S = w3 + z * DH; D = W3t + z * DH;
        k0 = (r / 11) * 32; n0 = (r % 11) * 256;
    } else if (b < 5824) {
        int idx = b - 5632;
        Kd = DDIM; Nn = HSDIM; S = sw1; D = sw1t;
        k0 = (idx / 6) * 32; n0 = (idx % 6) * 256;
    } else if (b < 6016) {
        int idx = b - 5824;
        Kd = DDIM; Nn = HSDIM; S = sw3; D = sw3t;
        k0 = (idx / 6) * 32; n0 = (idx % 6) * 256;
    } else {
        int idx = b - 6016;
        Kd = HSDIM; Nn = DDIM; S = sw2; D = sw2t;
        k0 = (idx / 4) * 32; n0 = (idx % 4) * 256;
    }
    tcast_tile(S, D, Kd, Nn, k0, n0, ld);
    (void)Kd;
}

// Fallback W2 transpose (aliased region, runs after fused_up) if ws too small.
__global__ __launch_bounds__(256) void tcast_k(const float* __restrict__ S,
                                               unsigned short* __restrict__ Dm) {
    __shared__ __align__(16) float ld[32 * 256];
    int b = blockIdx.x;                 // 8 experts x 352 tiles
    int z = b / 352, r = b % 352;
    size_t zo = (size_t)z * HDIM * DDIM;
    tcast_tile(S + zo, Dm + zo, HDIM, DDIM, (r / 4) * 32, (r % 4) * 256, ld);
}

// ---------------- fused up-projection (+ merged W2 tcast blocks) ----------------
// GEMM: tile 128(M) x 128(N), BK=64, 4 waves 2x2, per-wave 64x64 dual-accumulated
// (R12 body, verified 88us @ MfmaUtil 29.6%). Blocks [GRID_UP, GRID_UP+ntc) are
// W2 f32->bf16 chunked-transpose tiles: memory-bound work that drips into the
// spare block-slot per CU and hides under the GEMM's compute (R12 showed HBM at
// only 1.3 TB/s during fused_up -> ~5 TB/s headroom). Requires separate W2t.
__global__ __launch_bounds__(256, 2) void fused_up(
    const unsigned short* __restrict__ Xb,
    const int* __restrict__ rows_token,
    const int* __restrict__ offsets,
    const unsigned short* __restrict__ W1t,   // [8] chunked (Nn=HDIM)
    const unsigned short* __restrict__ W3t,
    const unsigned short* __restrict__ sw1t,  // chunked (Nn=HSDIM)
    const unsigned short* __restrict__ sw3t,
    unsigned short* __restrict__ Hg,          // [4096][H]
    unsigned short* __restrict__ Hs,          // [2048][HS]
    const int* __restrict__ wl, const int* __restrict__ wl_n,
    const float* __restrict__ w2,             // [8][HDIM][DDIM] f32 (merged tcast)
    unsigned short* __restrict__ W2t)         // [8] chunked (Nn=DDIM), separate
{
    __shared__ __align__(16) unsigned short smem[3 * 128 * 64];   // 48 KB
    if (blockIdx.x >= GRID_UP) {
        // merged W2 tcast block
        int idx = blockIdx.x - GRID_UP;
        int z = idx / 352, r = idx % 352;
        size_t zo = (size_t)z * HDIM * DDIM;
        tcast_tile(w2 + zo, W2t + zo, HDIM, DDIM,
                   (r / 4) * 32, (r % 4) * 256, (float*)smem);
        return;
    }
    int n_all = wl_n[0], n_r = wl_n[1];
    int live = NB_SH * n_all + (NB_UP - NB_SH) * n_r;
    int L = xcd_live_map(blockIdx.x, live);
    if (L < 0 || L >= live) return;
    int nb, it;
    if (L < NB_SH * n_all) { nb = L / n_all; it = L % n_all; }
    else { int L2 = L - NB_SH * n_all; nb = NB_SH + L2 / n_r; it = L2 % n_r; }
    int pk = wl[it];
    int z = pk >> 16, m0 = pk & 0xffff;
    bool sh = (z == EEXP);
    int roff, Ne, Nn;
    const unsigned short *w1, *w3;
    unsigned short* Ho;
    if (sh) { roff = 0; Ne = T_TOK; Nn = HSDIM; w1 = sw1t; w3 = sw3t; Ho = Hs; }
    else {
        roff = offsets[z]; Ne = offsets[z + 1] - roff; Nn = HDIM;
        w1 = W1t + (size_t)z * HDIM * DDIM;
        w3 = W3t + (size_t)z * HDIM * DDIM;
        Ho = Hg;
    }
    int n0 = nb * 128;
    if (n0 >= Nn) return;

    unsigned short* As  = smem;
    unsigned short* B1s = smem + 8192;
    unsigned short* B3s = smem + 16384;

    int tid = threadIdx.x, lane = tid & 63, wid = tid >> 6;
    int wr = wid >> 1, wc = wid & 1;          // per-wave 64 rows x 64 cols
    int cl = (lane & 7) ^ (lane >> 3);        // swizzled chunk index 0..7

    size_t bstep = (size_t)64 * Nn;           // chunked-layout K-step stride (u16)
    const unsigned short* pA[4];
    const unsigned short *pB1[4], *pB3[4];
#pragma unroll
    for (int j = 0; j < 4; j++) {
        int lr = (wid * 4 + j) * 8 + (lane >> 3);
        int gr = m0 + lr; if (gr >= Ne) gr = Ne - 1;
        int tok = sh ? gr : rows_token[roff + gr];
        pA[j]  = Xb + (size_t)tok * DDIM + cl * 8;
        size_t boff = ((size_t)(cl >> 2) * Nn + n0 + lr) * 32 + (cl & 3) * 8;
        pB1[j] = w1 + boff;
        pB3[j] = w3 + boff;
    }

    const f32x4 fz = {0.f, 0.f, 0.f, 0.f};
    f32x4 acc1[4][4], acc3[4][4];
#pragma unroll
    for (int mi = 0; mi < 4; mi++)
#pragma unroll
        for (int nj = 0; nj < 4; nj++) { acc1[mi][nj] = fz; acc3[mi][nj] = fz; }

#pragma unroll 1
    for (int ks = 0; ks < DDIM / BK; ks++) {
        __syncthreads();
#pragma unroll
        for (int j = 0; j < 4; j++) gload16(pA[j],  As  + (wid * 4 + j) * 512);
#pragma unroll
        for (int j = 0; j < 4; j++) gload16(pB1[j], B1s + (wid * 4 + j) * 512);
#pragma unroll
        for (int j = 0; j < 4; j++) gload16(pB3[j], B3s + (wid * 4 + j) * 512);
#pragma unroll
        for (int j = 0; j < 4; j++) { pA[j] += BK; pB1[j] += bstep; pB3[j] += bstep; }
        __syncthreads();
        int r = lane & 15, h = lane >> 4, sw = (lane & 7) << 4;
#pragma unroll
        for (int kk = 0; kk < 2; kk++) {
            int cb = (kk * 64 + h * 16) ^ sw;
            bf16x8 a[4], b1[4], b3[4];
#pragma unroll
            for (int mi = 0; mi < 4; mi++)
                a[mi] = *(const bf16x8*)((const char*)As + (wr * 64 + mi * 16 + r) * 128 + cb);
#pragma unroll
            for (int nj = 0; nj < 4; nj++) {
                b1[nj] = *(const bf16x8*)((const char*)B1s + (wc * 64 + nj * 16 + r) * 128 + cb);
                b3[nj] = *(const bf16x8*)((const char*)B3s + (wc * 64 + nj * 16 + r) * 128 + cb);
            }
#pragma unroll
            for (int mi = 0; mi < 4; mi++)
#pragma unroll
                for (int nj = 0; nj < 4; nj++) {
                    acc1[mi][nj] = __builtin_amdgcn_mfma_f32_16x16x32_bf16(a[mi], b1[nj], acc1[mi][nj], 0, 0, 0);
                    acc3[mi][nj] = __builtin_amdgcn_mfma_f32_16x16x32_bf16(a[mi], b3[nj], acc3[mi][nj], 0, 0, 0);
                }
        }
    }
    int r = lane & 15, h = lane >> 4;
#pragma unroll
    for (int mi = 0; mi < 4; mi++) {
#pragma unroll
        for (int nj = 0; nj < 4; nj++) {
            int col = n0 + wc * 64 + nj * 16 + r;
#pragma unroll
            for (int j = 0; j < 4; j++) {
                int row = wr * 64 + mi * 16 + h * 4 + j;
                if (m0 + row < Ne) {
                    float aa = acc1[mi][nj][j], bb = acc3[mi][nj][j];
                    float hv = (aa / (1.f + expf(-aa))) * bb;
                    Ho[(size_t)(roff + m0 + row) * Nn + col] = f2bf(hv);
                }
            }
        }
    }
}

// ---------------- down-projection + combine: out += gate * (H @ W2) ----------------
// tile 128(M) x 128(N), BK=64; B from chunked layout (Nn = DDIM). Single-buffer
// (R12 body — R14/R15 showed both dbuf variants regress). Epilogue: gated
// atomicAdd into pre-zeroed out (routed x gate, shared x 1).
__global__ __launch_bounds__(256) void gemm2(
    const unsigned short* __restrict__ Hg,
    const unsigned short* __restrict__ Hs,
    const unsigned short* __restrict__ W2t,   // [8] chunked (Nn=DDIM)
    const unsigned short* __restrict__ sw2t,  // chunked (Nn=DDIM)
    const int* __restrict__ offsets,
    const int* __restrict__ rows_token,
    const float* __restrict__ gate_row,
    float* __restrict__ out,
    const int* __restrict__ wl, const int* __restrict__ wl_n)
{
    int n_all = wl_n[0];
    int live = NB_DN * n_all;
    int L = xcd_live_map(blockIdx.x, live);
    if (L < 0 || L >= live) return;
    int nb = L / n_all, it = L % n_all;
    int pk = wl[it];
    int z = pk >> 16, m0 = pk & 0xffff;
    bool sh = (z == EEXP);
    int roff, Ne, Kd;
    const unsigned short *Ab, *Bb;
    if (sh) { roff = 0; Ne = T_TOK; Kd = HSDIM; Ab = Hs; Bb = sw2t; }
    else {
        roff = offsets[z]; Ne = offsets[z + 1] - roff; Kd = HDIM;
        Ab = Hg + (size_t)roff * HDIM;
        Bb = W2t + (size_t)z * DDIM * HDIM;
    }
    int n0 = nb * 128;

    __shared__ __align__(16) unsigned short As[128 * 64];
    __shared__ __align__(16) unsigned short Bs[128 * 64];

    int tid = threadIdx.x, lane = tid & 63, wid = tid >> 6;
    int wr = wid >> 1, wc = wid & 1;
    int cl = (lane & 7) ^ (lane >> 3);

    const size_t bstep = (size_t)64 * DDIM;   // chunked stride (u16), Nn = DDIM
    const unsigned short* pA[4];
    const unsigned short* pB[4];
#pragma unroll
    for (int j = 0; j < 4; j++) {
        int lr = (wid * 4 + j) * 8 + (lane >> 3);
        int gr = m0 + lr; if (gr >= Ne) gr = Ne - 1;
        pA[j] = Ab + (size_t)gr * Kd + cl * 8;
        pB[j] = Bb + ((size_t)(cl >> 2) * DDIM + n0 + lr) * 32 + (cl & 3) * 8;
    }

    const f32x4 fz = {0.f, 0.f, 0.f, 0.f};
    f32x4 acc[4][4];
#pragma unroll
    for (int mi = 0; mi < 4; mi++)
#pragma unroll
        for (int nj = 0; nj < 4; nj++) acc[mi][nj] = fz;

    int nks = Kd / BK;
#pragma unroll 1
    for (int ks = 0; ks < nks; ks++) {
        __syncthreads();
#pragma unroll
        for (int j = 0; j < 4; j++) gload16(pA[j], As + (wid * 4 + j) * 512);
#pragma unroll
        for (int j = 0; j < 4; j++) gload16(pB[j], Bs + (wid * 4 + j) * 512);
#pragma unroll
        for (int j = 0; j < 4; j++) { pA[j] += BK; pB[j] += bstep; }
        __syncthreads();
        int r = lane & 15, h = lane >> 4, sw = (lane & 7) << 4;
#pragma unroll
        for (int kk = 0; kk < 2; kk++) {
            int cb = (kk * 64 + h * 16) ^ sw;
            bf16x8 a[4], b[4];
#pragma unroll
            for (int mi = 0; mi < 4; mi++)
                a[mi] = *(const bf16x8*)((const char*)As + (wr * 64 + mi * 16 + r) * 128 + cb);
#pragma unroll
            for (int nj = 0; nj < 4; nj++)
                b[nj] = *(const bf16x8*)((const char*)Bs + (wc * 64 + nj * 16 + r) * 128 + cb);
#pragma unroll
            for (int mi = 0; mi < 4; mi++)
#pragma unroll
                for (int nj = 0; nj < 4; nj++)
                    acc[mi][nj] = __builtin_amdgcn_mfma_f32_16x16x32_bf16(a[mi], b[nj], acc[mi][nj], 0, 0, 0);
        }
    }
    int r = lane & 15, h = lane >> 4;
#pragma unroll
    for (int mi = 0; mi < 4; mi++) {
#pragma unroll
        for (int j = 0; j < 4; j++) {
            int row = wr * 64 + mi * 16 + h * 4 + j;
            if (m0 + row >= Ne) continue;
            int tok; float g;
            if (sh) { tok = m0 + row; g = 1.f; }
            else {
                int rr = roff + m0 + row;
                tok = rows_token[rr];
                g = gate_row[rr];
            }
            float* orow = out + (size_t)tok * DDIM;
#pragma unroll
            for (int nj = 0; nj < 4; nj++) {
                int col = n0 + wc * 64 + nj * 16 + r;
                atomicAdd(orow + col, g * acc[mi][nj][j]);
            }
        }
    }
}

// ---------------- launch ----------------
extern "C" void kernel_launch(void* const* d_in, const int* in_sizes, int n_in,
                              void* d_out, int out_size, void* d_ws, size_t ws_size,
                              hipStream_t stream) {
    const float* x   = (const float*)d_in[0];
    const float* gw  = (const float*)d_in[1];
    const float* w1  = (const float*)d_in[2];
    const float* w3  = (const float*)d_in[3];
    const float* w2  = (const float*)d_in[4];
    const float* sw1 = (const float*)d_in[5];
    const float* sw3 = (const float*)d_in[6];
    const float* sw2 = (const float*)d_in[7];
    float* out = (float*)d_out;
    char* ws = (char*)d_ws;

    const size_t MB = 1048576;
    int*   counts     = (int*)(ws);
    int*   offsets    = (int*)(ws + 64);
    int*   cursors    = (int*)(ws + 128);
    int*   wl_n       = (int*)(ws + 192);     // [0]=total, [1]=routed
    int*   wl         = (int*)(ws + 256);
    int*   topi       = (int*)(ws + 512);
    float* topw       = (float*)(ws + 16896);
    int*   rows_token = (int*)(ws + 33280);
    float* gate_row   = (float*)(ws + 49664);
    unsigned short* Xb   = (unsigned short*)(ws + 1 * MB);    // 4 MB
    unsigned short* sw1t = (unsigned short*)(ws + 6 * MB);    // 3 MB
    unsigned short* sw3t = (unsigned short*)(ws + 9 * MB);    // 3 MB
    unsigned short* sw2t = (unsigned short*)(ws + 12 * MB);   // 3 MB
    unsigned short* Hg   = (unsigned short*)(ws + 16 * MB);   // 22 MB
    unsigned short* Hs   = (unsigned short*)(ws + 40 * MB);   // 6 MB
    unsigned short* W1t  = (unsigned short*)(ws + 64 * MB);   // 44 MB
    unsigned short* W3t  = (unsigned short*)(ws + 108 * MB);  // 44 MB (ends 152 MB)

    // W2t: separate region when workspace allows (merged-tcast path needs it,
    // no alias race); else alias W1t + late transpose (R12 behavior exactly).
    bool sepW2 = (ws_size >= 196 * MB);
    unsigned short* W2t = sepW2 ? (unsigned short*)(ws + 152 * MB) : W1t;

    // routing
    init_k<<<1, 64, 0, stream>>>(counts, cursors);
    gate_k<<<T_TOK / 4, 256, 0, stream>>>(x, gw, topi, topw, counts);
    scan_k<<<1, 64, 0, stream>>>(counts, offsets, wl, wl_n);
    build_k<<<T_TOK / 256, 256, 0, stream>>>(topi, topw, offsets, cursors,
                                             rows_token, gate_row);

    // zero out (gemm2 accumulates into it atomically)
    hipMemsetAsync(out, 0, (size_t)T_TOK * DDIM * sizeof(float), stream);

    // pre-pass: W1/W3/shared transposes + xcast (W2 merged into fused_up)
    prep_k<<<PREP_GRID, 256, 0, stream>>>(x, w1, w3, sw1, sw3, sw2,
                                          Xb, W1t, W3t, sw1t, sw3t, sw2t);

    // up-projection; when sepW2, W2-tcast blocks ride along (GEMM blocks first,
    // tcast drips into spare CU slots and hides under the GEMM)
    fused_up<<<GRID_UP + (sepW2 ? TCAST_W2 : 0), 256, 0, stream>>>(
        Xb, rows_token, offsets, W1t, W3t, sw1t, sw3t, Hg, Hs, wl, wl_n,
        w2, W2t);

    // fallback W2 transpose into aliased region (only if ws too small)
    if (!sepW2)
        tcast_k<<<TCAST_W2, 256, 0, stream>>>(w2, W2t);

    // down-projection + gated combine (atomicAdd into out)
    gemm2<<<GRID_DN, 256, 0, stream>>>(
        Hg, Hs, W2t, sw2t, offsets, rows_token, gate_row, out, wl, wl_n);
}